// Round 1
// baseline (314.062 us; speedup 1.0000x reference)
//
#include <hip/hip_runtime.h>

// LSTMModel: B=4096, T=512, IN=2, H=12, OUT=2, fp32.
// Mapping: 16-lane sub-group per batch element (12 active lanes = hidden units).
// 256 blocks x 256 threads = 1 block/CU across all 256 CUs.
// Weights live in registers (fully unrolled constant indexing).
// h broadcast via ds_bpermute (intra-wave, no LDS alloc, no barriers).

namespace {
constexpr int H  = 12;
constexpr int T  = 512;
constexpr int IN = 2;

__device__ __forceinline__ float rcp_(float v) { return __builtin_amdgcn_rcpf(v); }
__device__ __forceinline__ float sigm_(float v) { return rcp_(1.0f + __expf(-v)); }
__device__ __forceinline__ float tanh_(float v) {
    // tanh(x) = 1 - 2/(exp(2x)+1)
    return fmaf(-2.0f, rcp_(1.0f + __expf(2.0f * v)), 1.0f);
}
__device__ __forceinline__ float bperm_(int addr, float v) {
    return __int_as_float(__builtin_amdgcn_ds_bpermute(addr, __float_as_int(v)));
}
} // namespace

__global__ __launch_bounds__(256, 1) void lstm2_fc_kernel(
    const float* __restrict__ x,      // (4096, 512, 2)
    const float* __restrict__ W_ih0,  // (48, 2)
    const float* __restrict__ W_hh0,  // (48, 12)
    const float* __restrict__ b_ih0,  // (48)
    const float* __restrict__ b_hh0,  // (48)
    const float* __restrict__ W_ih1,  // (48, 12)
    const float* __restrict__ W_hh1,  // (48, 12)
    const float* __restrict__ b_ih1,  // (48)
    const float* __restrict__ b_hh1,  // (48)
    const float* __restrict__ fc_W,   // (2, 12)
    const float* __restrict__ fc_b,   // (2)
    float* __restrict__ out)          // (4096, 2)
{
    const int tid  = threadIdx.x;
    const int lane = tid & 63;
    const int u    = tid & 15;          // unit slot within group (0..15, 12 active)
    const int grp  = tid >> 4;          // group within block (0..15)
    const int b    = blockIdx.x * 16 + grp;
    const int uc   = (u < H) ? u : 0;   // clamped unit for safe (unused) loads

    // bpermute byte address of this group's lane j within the wave:
    // group base lane = lane & 48 -> byte addr = (lane&48)*4
    const int pbase = (lane & 48) << 2;

    // ---------------- load weights into registers ----------------
    float wih0[4][IN], whh0[4][H], wih1[4][H], whh1[4][H];
    float bias0[4], bias1[4];
#pragma unroll
    for (int g = 0; g < 4; ++g) {
        const int r = g * H + uc;       // gate row (order: i, f, g, o)
        bias0[g] = b_ih0[r] + b_hh0[r];
        bias1[g] = b_ih1[r] + b_hh1[r];
        wih0[g][0] = W_ih0[r * IN + 0];
        wih0[g][1] = W_ih0[r * IN + 1];
#pragma unroll
        for (int j = 0; j < H; ++j) {
            whh0[g][j] = W_hh0[r * H + j];
            wih1[g][j] = W_ih1[r * H + j];
            whh1[g][j] = W_hh1[r * H + j];
        }
    }

    // ---------------- state ----------------
    float c0 = 0.0f, c1 = 0.0f;
    float h0b[H], h1b[H];               // broadcast copies of full h vectors
#pragma unroll
    for (int j = 0; j < H; ++j) { h0b[j] = 0.0f; h1b[j] = 0.0f; }

    const float* xb = x + (size_t)b * T * IN;
    float2 xc = *(const float2*)xb;     // x[b, 0, :]

    for (int t = 0; t < T; ++t) {
        // prefetch next x (clamped at the end to stay in bounds)
        const int tn = (t < T - 1) ? (t + 1) : t;
        const float2 xn = *(const float2*)(xb + tn * IN);

        // ---- layer 0 gates: bias + W_ih0 . x[t] + W_hh0 . h0[t-1] ----
        float a0[4];
#pragma unroll
        for (int g = 0; g < 4; ++g) {
            float acc = fmaf(wih0[g][0], xc.x, bias0[g]);
            acc = fmaf(wih0[g][1], xc.y, acc);
#pragma unroll
            for (int j = 0; j < H; ++j) acc = fmaf(whh0[g][j], h0b[j], acc);
            a0[g] = acc;
        }
        {
            const float i0 = sigm_(a0[0]);
            const float f0 = sigm_(a0[1]);
            const float g0 = tanh_(a0[2]);
            const float o0 = sigm_(a0[3]);
            c0 = fmaf(f0, c0, i0 * g0);
            const float h0 = o0 * tanh_(c0);
            // broadcast new h0 across the 16-lane group (lanes 0..11 are sources)
#pragma unroll
            for (int j = 0; j < H; ++j) h0b[j] = bperm_(pbase + 4 * j, h0);
        }

        // ---- layer 1 gates: bias + W_ih1 . h0[t] + W_hh1 . h1[t-1] ----
        // (W_hh1 . h1b first: h1b is already in registers, hides bpermute latency)
        float a1[4];
#pragma unroll
        for (int g = 0; g < 4; ++g) {
            float acc = bias1[g];
#pragma unroll
            for (int j = 0; j < H; ++j) acc = fmaf(whh1[g][j], h1b[j], acc);
#pragma unroll
            for (int j = 0; j < H; ++j) acc = fmaf(wih1[g][j], h0b[j], acc);
            a1[g] = acc;
        }
        {
            const float i1 = sigm_(a1[0]);
            const float f1 = sigm_(a1[1]);
            const float g1 = tanh_(a1[2]);
            const float o1 = sigm_(a1[3]);
            c1 = fmaf(f1, c1, i1 * g1);
            const float h1 = o1 * tanh_(c1);
#pragma unroll
            for (int j = 0; j < H; ++j) h1b[j] = bperm_(pbase + 4 * j, h1);
        }

        xc = xn;
    }

    // ---------------- final FC on lane 0 of each group ----------------
    if (u == 0) {
        float r0 = fc_b[0];
        float r1 = fc_b[1];
#pragma unroll
        for (int j = 0; j < H; ++j) {
            r0 = fmaf(fc_W[j],      h1b[j], r0);
            r1 = fmaf(fc_W[H + j],  h1b[j], r1);
        }
        float2 res; res.x = r0; res.y = r1;
        *(float2*)(out + (size_t)b * 2) = res;
    }
}

extern "C" void kernel_launch(void* const* d_in, const int* in_sizes, int n_in,
                              void* d_out, int out_size, void* d_ws, size_t ws_size,
                              hipStream_t stream) {
    const float* x     = (const float*)d_in[0];
    const float* W_ih0 = (const float*)d_in[1];
    const float* W_hh0 = (const float*)d_in[2];
    const float* b_ih0 = (const float*)d_in[3];
    const float* b_hh0 = (const float*)d_in[4];
    const float* W_ih1 = (const float*)d_in[5];
    const float* W_hh1 = (const float*)d_in[6];
    const float* b_ih1 = (const float*)d_in[7];
    const float* b_hh1 = (const float*)d_in[8];
    const float* fc_W  = (const float*)d_in[9];
    const float* fc_b  = (const float*)d_in[10];
    float* out = (float*)d_out;

    // 4096 batch elements / 16 per block (16-lane group each) = 256 blocks
    lstm2_fc_kernel<<<256, 256, 0, stream>>>(
        x, W_ih0, W_hh0, b_ih0, b_hh0,
        W_ih1, W_hh1, b_ih1, b_hh1, fc_W, fc_b, out);
}

// Round 2
// 276.217 us; speedup vs baseline: 1.1370x; 1.1370x over previous
//
#include <hip/hip_runtime.h>

// LSTMModel: B=4096, T=512, IN=2, H=12, OUT=2, fp32.
// Decomposition: 32 lanes per batch element, 2 elements per wave.
//   lane-in-elem p = u + 16*half ; u = hidden unit (0..15, 12 active)
//   half 0 computes gates {i, f}; half 1 computes gates {g, o}.
// 512 blocks x 256 threads = 2 blocks/CU = 2 waves/SIMD (latency hiding).
// Cross-lane exchange via ds_swizzle immediates (no LDS alloc, no barriers):
//   - gather g,o to the c-lane:  lane ^ 16      (imm 0x401F)
//   - broadcast h[j] to 32 lanes: or-mask = j   (imm j<<5)

namespace {
constexpr int H  = 12;
constexpr int T  = 512;
constexpr int IN = 2;

__device__ __forceinline__ float rcp_(float v) { return __builtin_amdgcn_rcpf(v); }
__device__ __forceinline__ float sigm_(float v) { return rcp_(1.0f + __expf(-v)); }
__device__ __forceinline__ float tanh_(float v) {
    // tanh(x) = 1 - 2/(exp(2x)+1)
    return fmaf(-2.0f, rcp_(1.0f + __expf(2.0f * v)), 1.0f);
}
template <int IMM>
__device__ __forceinline__ float swzf(float v) {
    return __int_as_float(__builtin_amdgcn_ds_swizzle(__float_as_int(v), IMM));
}
} // namespace

// broadcast lane j (within each 32-lane half) to all lanes of that half
#define BC12(dst, v)                                                         \
    do {                                                                     \
        dst[0]  = swzf<(0 << 5)>(v);  dst[1]  = swzf<(1 << 5)>(v);           \
        dst[2]  = swzf<(2 << 5)>(v);  dst[3]  = swzf<(3 << 5)>(v);           \
        dst[4]  = swzf<(4 << 5)>(v);  dst[5]  = swzf<(5 << 5)>(v);           \
        dst[6]  = swzf<(6 << 5)>(v);  dst[7]  = swzf<(7 << 5)>(v);           \
        dst[8]  = swzf<(8 << 5)>(v);  dst[9]  = swzf<(9 << 5)>(v);           \
        dst[10] = swzf<(10 << 5)>(v); dst[11] = swzf<(11 << 5)>(v);          \
    } while (0)

#define XOR16 0x401F  // and=0x1F, or=0, xor=16 -> lane ^ 16

__global__ __launch_bounds__(256, 2) void lstm2_fc_kernel(
    const float* __restrict__ x,      // (4096, 512, 2)
    const float* __restrict__ W_ih0,  // (48, 2)
    const float* __restrict__ W_hh0,  // (48, 12)
    const float* __restrict__ b_ih0,  // (48)
    const float* __restrict__ b_hh0,  // (48)
    const float* __restrict__ W_ih1,  // (48, 12)
    const float* __restrict__ W_hh1,  // (48, 12)
    const float* __restrict__ b_ih1,  // (48)
    const float* __restrict__ b_hh1,  // (48)
    const float* __restrict__ fc_W,   // (2, 12)
    const float* __restrict__ fc_b,   // (2)
    float* __restrict__ out)          // (4096, 2)
{
    const int tid  = threadIdx.x;
    const int p    = tid & 31;          // lane within element
    const int u    = p & 15;            // unit slot (12 active)
    const int half = p >> 4;            // 0: gates i,f   1: gates g,o
    const int b    = blockIdx.x * 8 + (tid >> 5);
    const int uc   = (u < H) ? u : 0;   // clamped for safe (unused) loads

    // gate rows (weight row order: i[0:12), f[12:24), g[24:36), o[36:48))
    const int rA = (2 * half) * H + uc;   // i or g
    const int rB = rA + H;                // f or o

    // activation shaping: half0 -> sigmoid(x); half1 gate A -> tanh via
    // tanh(x) = 2*sigmoid(2x) - 1  (divergence-free)
    const float preA = half ? 2.0f : 1.0f;
    const float pmA  = half ? 2.0f : 1.0f;
    const float paA  = half ? -1.0f : 0.0f;

    // ---------------- load weights into registers ----------------
    float wih0A[IN], wih0B[IN];
    float whh0A[H], whh0B[H], wih1A[H], wih1B[H], whh1A[H], whh1B[H];
    wih0A[0] = W_ih0[rA * IN + 0]; wih0A[1] = W_ih0[rA * IN + 1];
    wih0B[0] = W_ih0[rB * IN + 0]; wih0B[1] = W_ih0[rB * IN + 1];
#pragma unroll
    for (int j = 0; j < H; ++j) {
        whh0A[j] = W_hh0[rA * H + j];  whh0B[j] = W_hh0[rB * H + j];
        wih1A[j] = W_ih1[rA * H + j];  wih1B[j] = W_ih1[rB * H + j];
        whh1A[j] = W_hh1[rA * H + j];  whh1B[j] = W_hh1[rB * H + j];
    }
    const float biasA0 = b_ih0[rA] + b_hh0[rA];
    const float biasB0 = b_ih0[rB] + b_hh0[rB];
    const float biasA1 = b_ih1[rA] + b_hh1[rA];
    const float biasB1 = b_ih1[rB] + b_hh1[rB];

    // ---------------- state ----------------
    float c0 = 0.0f, c1 = 0.0f;
    float h0b[H], h1b[H];
#pragma unroll
    for (int j = 0; j < H; ++j) { h0b[j] = 0.0f; h1b[j] = 0.0f; }

    const float* xb = x + (size_t)b * T * IN;
    float2 xc = *(const float2*)xb;

    for (int t = 0; t < T; ++t) {
        const int tn = (t < T - 1) ? (t + 1) : t;
        const float2 xn = *(const float2*)(xb + tn * IN);

        // ---- layer 0: two gate dot products per lane ----
        float aA = fmaf(wih0A[0], xc.x, biasA0);
        float aB = fmaf(wih0B[0], xc.x, biasB0);
        aA = fmaf(wih0A[1], xc.y, aA);
        aB = fmaf(wih0B[1], xc.y, aB);
#pragma unroll
        for (int j = 0; j < H; ++j) {
            aA = fmaf(whh0A[j], h0b[j], aA);
            aB = fmaf(whh0B[j], h0b[j], aB);
        }
        const float sA0 = fmaf(pmA, sigm_(preA * aA), paA);  // i (h0) / g (h1)
        const float sB0 = sigm_(aB);                         // f (h0) / o (h1)
        // gather g,o from the partner half; update c,h on half-0 lanes
        const float gv0 = swzf<XOR16>(sA0);
        const float ov0 = swzf<XOR16>(sB0);
        c0 = fmaf(sB0, c0, sA0 * gv0);
        const float h0 = ov0 * tanh_(c0);
        BC12(h0b, h0);   // valid sources are lanes p=0..11 (the c-lanes)

        // ---- layer 1: W_hh1 . h1(t-1) first (ready), then W_ih1 . h0(t) ----
        float a1A = biasA1, a1B = biasB1;
#pragma unroll
        for (int j = 0; j < H; ++j) {
            a1A = fmaf(whh1A[j], h1b[j], a1A);
            a1B = fmaf(whh1B[j], h1b[j], a1B);
        }
#pragma unroll
        for (int j = 0; j < H; ++j) {
            a1A = fmaf(wih1A[j], h0b[j], a1A);
            a1B = fmaf(wih1B[j], h0b[j], a1B);
        }
        const float sA1 = fmaf(pmA, sigm_(preA * a1A), paA);
        const float sB1 = sigm_(a1B);
        const float gv1 = swzf<XOR16>(sA1);
        const float ov1 = swzf<XOR16>(sB1);
        c1 = fmaf(sB1, c1, sA1 * gv1);
        const float h1 = ov1 * tanh_(c1);
        BC12(h1b, h1);

        xc = xn;
    }

    // ---------------- final FC (one lane per element) ----------------
    if (p == 0) {
        float r0 = fc_b[0];
        float r1 = fc_b[1];
#pragma unroll
        for (int j = 0; j < H; ++j) {
            r0 = fmaf(fc_W[j],     h1b[j], r0);
            r1 = fmaf(fc_W[H + j], h1b[j], r1);
        }
        float2 res; res.x = r0; res.y = r1;
        *(float2*)(out + (size_t)b * 2) = res;
    }
}

extern "C" void kernel_launch(void* const* d_in, const int* in_sizes, int n_in,
                              void* d_out, int out_size, void* d_ws, size_t ws_size,
                              hipStream_t stream) {
    const float* x     = (const float*)d_in[0];
    const float* W_ih0 = (const float*)d_in[1];
    const float* W_hh0 = (const float*)d_in[2];
    const float* b_ih0 = (const float*)d_in[3];
    const float* b_hh0 = (const float*)d_in[4];
    const float* W_ih1 = (const float*)d_in[5];
    const float* W_hh1 = (const float*)d_in[6];
    const float* b_ih1 = (const float*)d_in[7];
    const float* b_hh1 = (const float*)d_in[8];
    const float* fc_W  = (const float*)d_in[9];
    const float* fc_b  = (const float*)d_in[10];
    float* out = (float*)d_out;

    // 4096 elements / (8 per block: 4 waves x 2 elems) = 512 blocks
    lstm2_fc_kernel<<<512, 256, 0, stream>>>(
        x, W_ih0, W_hh0, b_ih0, b_hh0,
        W_ih1, W_hh1, b_ih1, b_hh1, fc_W, fc_b, out);
}